// Round 19
// baseline (920.544 us; speedup 1.0000x reference)
//
#include <hip/hip_runtime.h>
#include <math.h>

#define NC    10
#define BATCH 256
#define IC    1152
#define LDIM  8
#define OC    16

#define NCH   96
#define CH    (IC/NCH)        // 12 i's per block
#define NBLK  (NC*NCH)        // 960 blocks = 3.75/CU (co-resident at 4/CU cap)
#define NTHR  256
#define NTOT  (NC*BATCH*OC)   // 40960
#define NRED  160             // kR virtual blocks / n2 partials
#define KPG   (NCH/4)         // 24 chunks per wave-group in kR

typedef float f32x2 __attribute__((ext_vector_type(2)));

__device__ __forceinline__ int xcd_swizzle(int bid, int nwg) {
    int cpx = nwg >> 3;
    return (bid & 7) * cpx + (bid >> 3);
}

// Decentralized slot barrier (fixes both R6 failure modes):
//  - per-block slot release-store: ZERO atomic contention (no RMW at all)
//  - RELAXED spin polls (no per-poll cache invalidation), one wave polls
//  - single acquire fence (__threadfence) after all slots observed
// Monotonic epochs; slots zeroed by hipMemsetAsync each launch.
__device__ __forceinline__ void gbar(unsigned* slots, unsigned epoch) {
    __syncthreads();                      // all block threads' stores issued
    if (threadIdx.x == 0)
        __hip_atomic_store(slots + blockIdx.x, epoch, __ATOMIC_RELEASE,
                           __HIP_MEMORY_SCOPE_AGENT);
    if (threadIdx.x < 64) {               // one wave polls 15 slots per lane
        for (int sl = threadIdx.x; sl < NBLK; sl += 64)
            while (__hip_atomic_load(slots + sl, __ATOMIC_RELAXED,
                                     __HIP_MEMORY_SCOPE_AGENT) < epoch)
                __builtin_amdgcn_s_sleep(1);
    }
    __threadfence();                      // acquire: pull remote L2 data
    __syncthreads();
}

// ---------------------------------------------------------------------------
// pass_A: iter-0 s partials (c = 1/256). R14 kA body, verbatim.
// ---------------------------------------------------------------------------
__device__ __forceinline__ void pass_A(const float* __restrict__ xT,
                                       const float* __restrict__ w,
                                       float* __restrict__ s_part,
                                       int n, int ch, int t)
{
    int i0 = ch * CH;
    f32x2 sp2[8];
#pragma unroll
    for (int j = 0; j < 8; ++j) sp2[j] = (f32x2){0.f, 0.f};

    for (int ii = 0; ii < CH; ++ii) {
        int i = i0 + ii;
        const float4* xp = reinterpret_cast<const float4*>(xT)
                         + ((size_t)i * BATCH + t) * 2;
        float4 xa = xp[0], xb = xp[1];
        float xr[8] = {xa.x, xa.y, xa.z, xa.w, xb.x, xb.y, xb.z, xb.w};
        const f32x2* wp2 = reinterpret_cast<const f32x2*>(
            w + (size_t)__builtin_amdgcn_readfirstlane((n * IC + i) * (LDIM * OC)));
#pragma unroll
        for (int l = 0; l < LDIM; ++l) {
            f32x2 xl = {xr[l], xr[l]};
#pragma unroll
            for (int j = 0; j < 8; ++j)
                sp2[j] += wp2[l * 8 + j] * xl;    // v_pk_fma_f32
        }
    }
    float4* dst = reinterpret_cast<float4*>(s_part)
                + (((size_t)ch * NC + n) * BATCH + t) * 4;
    const float inv = 1.0f / 256.0f;
    dst[0] = make_float4(sp2[0].x*inv, sp2[0].y*inv, sp2[1].x*inv, sp2[1].y*inv);
    dst[1] = make_float4(sp2[2].x*inv, sp2[2].y*inv, sp2[3].x*inv, sp2[3].y*inv);
    dst[2] = make_float4(sp2[4].x*inv, sp2[4].y*inv, sp2[5].x*inv, sp2[5].y*inv);
    dst[3] = make_float4(sp2[6].x*inv, sp2[6].y*inv, sp2[7].x*inv, sp2[7].y*inv);
}

// ---------------------------------------------------------------------------
// pass_R: s reduction + n2 partial. R14 kR body; bid < NRED only.
// ---------------------------------------------------------------------------
__device__ __forceinline__ void pass_R(const float* __restrict__ s_part,
                                       float* __restrict__ s,
                                       float* __restrict__ n2_part,
                                       int bid, int t, float4 (*lds)[64])
{
    int lane = t & 63, g = t >> 6;
    int idx0 = bid * 256;
    const float* base = s_part + idx0 + lane * 4;
    float4 a0 = make_float4(0,0,0,0), a1 = a0, a2 = a0, a3 = a0;
    for (int k = 0; k < KPG; k += 4) {
        float4 v0 = *reinterpret_cast<const float4*>(base + (size_t)(g*KPG + k    ) * NTOT);
        float4 v1 = *reinterpret_cast<const float4*>(base + (size_t)(g*KPG + k + 1) * NTOT);
        float4 v2 = *reinterpret_cast<const float4*>(base + (size_t)(g*KPG + k + 2) * NTOT);
        float4 v3 = *reinterpret_cast<const float4*>(base + (size_t)(g*KPG + k + 3) * NTOT);
        a0.x += v0.x; a0.y += v0.y; a0.z += v0.z; a0.w += v0.w;
        a1.x += v1.x; a1.y += v1.y; a1.z += v1.z; a1.w += v1.w;
        a2.x += v2.x; a2.y += v2.y; a2.z += v2.z; a2.w += v2.w;
        a3.x += v3.x; a3.y += v3.y; a3.z += v3.z; a3.w += v3.w;
    }
    float4 a = make_float4((a0.x+a1.x)+(a2.x+a3.x), (a0.y+a1.y)+(a2.y+a3.y),
                           (a0.z+a1.z)+(a2.z+a3.z), (a0.w+a1.w)+(a2.w+a3.w));
    lds[g][lane] = a;
    __syncthreads();
    if (t < 64) {
        float4 s0 = lds[0][t], s1 = lds[1][t], s2 = lds[2][t], s3 = lds[3][t];
        float4 sv = make_float4((s0.x+s1.x)+(s2.x+s3.x), (s0.y+s1.y)+(s2.y+s3.y),
                                (s0.z+s1.z)+(s2.z+s3.z), (s0.w+s1.w)+(s2.w+s3.w));
        *reinterpret_cast<float4*>(s + idx0 + t * 4) = sv;
        float q = sv.x*sv.x + sv.y*sv.y + sv.z*sv.z + sv.w*sv.w;
#pragma unroll
        for (int m = 32; m >= 1; m >>= 1) q += __shfl_xor(q, m, 64);
        if (t == 0) n2_part[bid] = q;
    }
}

// ---------------------------------------------------------------------------
// pass_B: fused routing step, ii-paired, betaT-free. R14 kB body, verbatim.
// ---------------------------------------------------------------------------
template<int MODE>
__device__ __forceinline__ void pass_B(
    const float* __restrict__ xT, const float* __restrict__ w,
    const float* __restrict__ s1, const float* __restrict__ n2p1,
    const float* __restrict__ s2, const float* __restrict__ n2p2,
    float* __restrict__ s_part, int n, int ch, int t,
    float (*redA)[2][4], float* redW)
{
    int lane = t & 63, wid = t >> 6;
    int i0 = ch * CH;

    float q1 = (t < NRED) ? n2p1[t] : 0.f;
    float q2 = (MODE == 2 && t < NRED) ? n2p2[t] : 0.f;
#pragma unroll
    for (int m = 32; m >= 1; m >>= 1) {
        q1 += __shfl_xor(q1, m, 64);
        if (MODE == 2) q2 += __shfl_xor(q2, m, 64);
    }
    if (lane == 0) { redW[wid] = q1; redW[4 + wid] = q2; }
    __syncthreads();
    float n2a = (redW[0] + redW[1]) + (redW[2] + redW[3]);
    float sc1 = sqrtf(n2a) / (1.0f + n2a);

    f32x2 v2[8];
    {
        const f32x2* s1p = reinterpret_cast<const f32x2*>(s1)
                         + ((size_t)n * BATCH + t) * 8;
        f32x2 sv = {sc1, sc1};
#pragma unroll
        for (int j = 0; j < 8; ++j) v2[j] = s1p[j] * sv;
        if (MODE == 2) {
            float n2b = (redW[4] + redW[5]) + (redW[6] + redW[7]);
            float sc2 = sqrtf(n2b) / (1.0f + n2b);
            const f32x2* s2p = reinterpret_cast<const f32x2*>(s2)
                             + ((size_t)n * BATCH + t) * 8;
            f32x2 sw = {sc2, sc2};
#pragma unroll
            for (int j = 0; j < 8; ++j) v2[j] += s2p[j] * sw;
        }
    }

    f32x2 sp2[8];
#pragma unroll
    for (int j = 0; j < 8; ++j) sp2[j] = (f32x2){0.f, 0.f};

    for (int pr = 0; pr < CH / 2; ++pr) {
        int i = i0 + 2 * pr;
        const float4* xp = reinterpret_cast<const float4*>(xT)
                         + ((size_t)i * BATCH + t) * 2;
        float4 xa0 = xp[0], xb0 = xp[1];
        float4 xa1 = xp[2 * BATCH], xb1 = xp[2 * BATCH + 1];
        float xr0[8] = {xa0.x, xa0.y, xa0.z, xa0.w, xb0.x, xb0.y, xb0.z, xb0.w};
        float xr1[8] = {xa1.x, xa1.y, xa1.z, xa1.w, xb1.x, xb1.y, xb1.z, xb1.w};
        const f32x2* wp2 = reinterpret_cast<const f32x2*>(
            w + (size_t)__builtin_amdgcn_readfirstlane((n * IC + i) * (LDIM * OC)));

        f32x2 pA[8], pB[8];
#pragma unroll
        for (int j = 0; j < 8; ++j) { pA[j] = (f32x2){0.f,0.f}; pB[j] = (f32x2){0.f,0.f}; }
#pragma unroll
        for (int l = 0; l < LDIM; ++l) {
            f32x2 x0 = {xr0[l], xr0[l]}, x1 = {xr1[l], xr1[l]};
#pragma unroll
            for (int j = 0; j < 8; ++j) {
                pA[j] += wp2[l * 8 + j] * x0;
                pB[j] += wp2[64 + l * 8 + j] * x1;
            }
        }

        f32x2 dA = pA[0] * v2[0], dB = pB[0] * v2[0];
#pragma unroll
        for (int j = 1; j < 8; ++j) { dA += pA[j] * v2[j]; dB += pB[j] * v2[j]; }
        float betaA = dA.x + dA.y, betaB = dB.x + dB.y;

        float eA = __expf(betaA), eB = __expf(betaB);
        float esA = eA, esB = eB;
#pragma unroll
        for (int m = 1; m < 64; m <<= 1) {
            esA += __shfl_xor(esA, m, 64);
            esB += __shfl_xor(esB, m, 64);
        }
        if (lane == 0) { redA[pr & 1][0][wid] = esA; redA[pr & 1][1][wid] = esB; }
        __syncthreads();
        float denA = (redA[pr&1][0][0] + redA[pr&1][0][1])
                   + (redA[pr&1][0][2] + redA[pr&1][0][3]);
        float denB = (redA[pr&1][1][0] + redA[pr&1][1][1])
                   + (redA[pr&1][1][2] + redA[pr&1][1][3]);
        float cA = eA / denA, cB = eB / denB;
        f32x2 cA2 = {cA, cA}, cB2 = {cB, cB};
#pragma unroll
        for (int j = 0; j < 8; ++j) sp2[j] += cA2 * pA[j] + cB2 * pB[j];
    }

    float4* dst = reinterpret_cast<float4*>(s_part)
                + (((size_t)ch * NC + n) * BATCH + t) * 4;
    dst[0] = make_float4(sp2[0].x, sp2[0].y, sp2[1].x, sp2[1].y);
    dst[1] = make_float4(sp2[2].x, sp2[2].y, sp2[3].x, sp2[3].y);
    dst[2] = make_float4(sp2[4].x, sp2[4].y, sp2[5].x, sp2[5].y);
    dst[3] = make_float4(sp2[6].x, sp2[6].y, sp2[7].x, sp2[7].y);
}

// ---------------------------------------------------------------------------
// Persistent kernel: whole pipeline, 7 slot-barriers, R14 phase bodies.
// ---------------------------------------------------------------------------
__global__ __launch_bounds__(256, 4) void caps_persist(
    const float* __restrict__ x, const float* __restrict__ w,
    float* __restrict__ xT, float* __restrict__ s_part,
    float* __restrict__ s1, float* __restrict__ s2, float* __restrict__ s3,
    float* __restrict__ n2p1, float* __restrict__ n2p2, float* __restrict__ n2p3,
    unsigned* __restrict__ slots, float* __restrict__ out)
{
    __shared__ float4 ldsR[4][64];     // 4 KB (pass_R)
    __shared__ float redA[2][2][4];
    __shared__ float redW[8];

    int t = threadIdx.x;
    int bid = blockIdx.x;
    int wg = xcd_swizzle(bid, NBLK);
    int n = wg / NCH, ch = wg % NCH;

    // phase 0: transpose x -> xT (grid-strided)
    for (int u = bid * NTHR + t; u < IC * BATCH * 2; u += NBLK * NTHR) {
        int i = u >> 9, r = u & 511, b = r >> 1, h = r & 1;
        reinterpret_cast<float4*>(xT)[u] =
            reinterpret_cast<const float4*>(x)[((size_t)b * IC + i) * 2 + h];
    }
    gbar(slots, 1);

    pass_A(xT, w, s_part, n, ch, t);
    gbar(slots, 2);

    if (bid < NRED) pass_R(s_part, s1, n2p1, bid, t, ldsR);
    gbar(slots, 3);

    pass_B<1>(xT, w, s1, n2p1, s1, n2p1, s_part, n, ch, t, redA, redW);
    gbar(slots, 4);

    if (bid < NRED) pass_R(s_part, s2, n2p2, bid, t, ldsR);
    gbar(slots, 5);

    pass_B<2>(xT, w, s1, n2p1, s2, n2p2, s_part, n, ch, t, redA, redW);
    gbar(slots, 6);

    if (bid < NRED) pass_R(s_part, s3, n2p3, bid, t, ldsR);
    gbar(slots, 7);

    // final: out = s3 * scale (blocks 0..159)
    if (bid < NRED) {
        int lane = t & 63, wid = t >> 6;
        float q = (t < NRED) ? n2p3[t] : 0.f;
#pragma unroll
        for (int m = 32; m >= 1; m >>= 1) q += __shfl_xor(q, m, 64);
        if (lane == 0) redW[wid] = q;
        __syncthreads();
        float n2 = (redW[0] + redW[1]) + (redW[2] + redW[3]);
        float sc = sqrtf(n2) / (1.0f + n2);
        int idx = bid * 256 + t;
        out[idx] = s3[idx] * sc;
    }
}

// ---------------------------------------------------------------------------
extern "C" void kernel_launch(void* const* d_in, const int* in_sizes, int n_in,
                              void* d_out, int out_size, void* d_ws, size_t ws_size,
                              hipStream_t stream)
{
    const float* x = (const float*)d_in[0];   // [256,1152,8]
    const float* w = (const float*)d_in[1];   // [10,1152,8,16]
    float* out = (float*)d_out;               // 40960 floats
    float* ws  = (float*)d_ws;

    float* xT      = ws;                                  // 2,359,296
    float* s_part  = xT + (size_t)IC * BATCH * LDIM;      // 3,932,160
    float* s1      = s_part + (size_t)NCH * NTOT;         //    40,960
    float* s2      = s1 + NTOT;                           //    40,960
    float* s3      = s2 + NTOT;                           //    40,960
    float* n2p1    = s3 + NTOT;                           //       160
    float* n2p2    = n2p1 + NRED;                         //       160
    float* n2p3    = n2p2 + NRED;                         //       160
    unsigned* slots = (unsigned*)(n2p3 + NRED);           //       960
    // total ~26 MB of workspace

    (void)hipMemsetAsync(slots, 0, NBLK * sizeof(unsigned), stream);
    caps_persist<<<dim3(NBLK), dim3(NTHR), 0, stream>>>(
        x, w, xT, s_part, s1, s2, s3, n2p1, n2p2, n2p3, slots, out);
}

// Round 20
// 94.342 us; speedup vs baseline: 9.7575x; 9.7575x over previous
//
#include <hip/hip_runtime.h>
#include <math.h>

#define NC    10
#define BATCH 256
#define IC    1152
#define LDIM  8
#define OC    16

#define NCH   96
#define CH    (IC/NCH)        // 12 i's per block
#define NBLK  (NC*NCH)        // 960 blocks
#define NTHR  256
#define NTOT  (NC*BATCH*OC)   // 40960
#define NRED  160             // kR blocks / n2 partials
#define KPG   (NCH/4)         // 24 chunks per wave-group in kR

typedef float f32x2 __attribute__((ext_vector_type(2)));

// R8 n-major swizzle (best measured config)
__device__ __forceinline__ int xcd_swizzle(int bid, int nwg) {
    int cpx = nwg >> 3;
    return (bid & 7) * cpx + (bid >> 3);
}

// ---------------------------------------------------------------------------
// K0: transpose x[b][i][l] -> xT[i][b][l]
// ---------------------------------------------------------------------------
__global__ __launch_bounds__(256) void k0_xT(const float* __restrict__ x,
                                             float* __restrict__ xT)
{
    int u = blockIdx.x * 256 + threadIdx.x;       // < 589824
    int i = u >> 9, r = u & 511, b = r >> 1, h = r & 1;
    reinterpret_cast<float4*>(xT)[u] =
        reinterpret_cast<const float4*>(x)[((size_t)b * IC + i) * 2 + h];
}

// ---------------------------------------------------------------------------
// KA: iter-0 s partials (c uniform = 1/256). thread = b.
// ---------------------------------------------------------------------------
__global__ __launch_bounds__(256) void kA(
    const float* __restrict__ xT, const float* __restrict__ w,
    float* __restrict__ s_part)
{
    int wg = xcd_swizzle(blockIdx.x, NBLK);
    int n  = wg / NCH, ch = wg % NCH;
    int i0 = ch * CH;
    int t  = threadIdx.x;            // = b

    f32x2 sp2[8];
#pragma unroll
    for (int j = 0; j < 8; ++j) sp2[j] = (f32x2){0.f, 0.f};

    for (int ii = 0; ii < CH; ++ii) {
        int i = i0 + ii;
        const float4* xp = reinterpret_cast<const float4*>(xT)
                         + ((size_t)i * BATCH + t) * 2;
        float4 xa = xp[0], xb = xp[1];
        float xr[8] = {xa.x, xa.y, xa.z, xa.w, xb.x, xb.y, xb.z, xb.w};
        const f32x2* wp2 = reinterpret_cast<const f32x2*>(
            w + (size_t)__builtin_amdgcn_readfirstlane((n * IC + i) * (LDIM * OC)));
#pragma unroll
        for (int l = 0; l < LDIM; ++l) {
            f32x2 xl = {xr[l], xr[l]};
#pragma unroll
            for (int j = 0; j < 8; ++j)
                sp2[j] += wp2[l * 8 + j] * xl;    // v_pk_fma_f32
        }
    }
    float4* dst = reinterpret_cast<float4*>(s_part)
                + (((size_t)ch * NC + n) * BATCH + t) * 4;
    const float inv = 1.0f / 256.0f;
    dst[0] = make_float4(sp2[0].x*inv, sp2[0].y*inv, sp2[1].x*inv, sp2[1].y*inv);
    dst[1] = make_float4(sp2[2].x*inv, sp2[2].y*inv, sp2[3].x*inv, sp2[3].y*inv);
    dst[2] = make_float4(sp2[4].x*inv, sp2[4].y*inv, sp2[5].x*inv, sp2[5].y*inv);
    dst[3] = make_float4(sp2[6].x*inv, sp2[6].y*inv, sp2[7].x*inv, sp2[7].y*inv);
}

// ---------------------------------------------------------------------------
// KR: 160 blocks. Wave g sums chunks [g*24, g*24+24) as float4 with FOUR
// independent accumulators (fixed tree -> deterministic, ILP-4); LDS combine.
// ---------------------------------------------------------------------------
__global__ __launch_bounds__(256) void kR(const float* __restrict__ s_part,
                                          float* __restrict__ s,
                                          float* __restrict__ n2_part)
{
    __shared__ float4 lds[4][64];
    int t = threadIdx.x, lane = t & 63, g = t >> 6;
    int idx0 = blockIdx.x * 256;
    const float* base = s_part + idx0 + lane * 4;
    float4 a0 = make_float4(0,0,0,0), a1 = a0, a2 = a0, a3 = a0;
    for (int k = 0; k < KPG; k += 4) {
        float4 v0 = *reinterpret_cast<const float4*>(base + (size_t)(g*KPG + k    ) * NTOT);
        float4 v1 = *reinterpret_cast<const float4*>(base + (size_t)(g*KPG + k + 1) * NTOT);
        float4 v2 = *reinterpret_cast<const float4*>(base + (size_t)(g*KPG + k + 2) * NTOT);
        float4 v3 = *reinterpret_cast<const float4*>(base + (size_t)(g*KPG + k + 3) * NTOT);
        a0.x += v0.x; a0.y += v0.y; a0.z += v0.z; a0.w += v0.w;
        a1.x += v1.x; a1.y += v1.y; a1.z += v1.z; a1.w += v1.w;
        a2.x += v2.x; a2.y += v2.y; a2.z += v2.z; a2.w += v2.w;
        a3.x += v3.x; a3.y += v3.y; a3.z += v3.z; a3.w += v3.w;
    }
    float4 a = make_float4((a0.x+a1.x)+(a2.x+a3.x), (a0.y+a1.y)+(a2.y+a3.y),
                           (a0.z+a1.z)+(a2.z+a3.z), (a0.w+a1.w)+(a2.w+a3.w));
    lds[g][lane] = a;
    __syncthreads();
    if (t < 64) {
        float4 s0 = lds[0][t], s1 = lds[1][t], s2 = lds[2][t], s3 = lds[3][t];
        float4 sv = make_float4((s0.x+s1.x)+(s2.x+s3.x), (s0.y+s1.y)+(s2.y+s3.y),
                                (s0.z+s1.z)+(s2.z+s3.z), (s0.w+s1.w)+(s2.w+s3.w));
        *reinterpret_cast<float4*>(s + idx0 + t * 4) = sv;
        float q = sv.x*sv.x + sv.y*sv.y + sv.z*sv.z + sv.w*sv.w;
#pragma unroll
        for (int m = 32; m >= 1; m >>= 1) q += __shfl_xor(q, m, 64);
        if (t == 0) n2_part[blockIdx.x] = q;
    }
}

// ---------------------------------------------------------------------------
// KB: fused routing step, ii-paired, betaT-FREE.
// Linearity: beta_k = p . (v1 + ... + v_{k-1}), so dot against
//   MODE 1: v_eff = s1*sc1           (iter 2)
//   MODE 2: v_eff = s1*sc1 + s2*sc2  (iter 3)
// ---------------------------------------------------------------------------
template<int MODE>
__global__ __launch_bounds__(256) void kB(
    const float* __restrict__ xT, const float* __restrict__ w,
    const float* __restrict__ s1, const float* __restrict__ n2p1,
    const float* __restrict__ s2, const float* __restrict__ n2p2,
    float* __restrict__ s_part)
{
    __shared__ float redA[2][2][4];   // [pair parity][i-slot][wave]
    __shared__ float redW[8];
    int t = threadIdx.x, lane = t & 63, wid = t >> 6;
    int wg = xcd_swizzle(blockIdx.x, NBLK);
    int n  = wg / NCH, ch = wg % NCH;
    int i0 = ch * CH;

    // squash scale(s) from n2 partials (redundant per block, fixed order)
    float q1 = (t < NRED) ? n2p1[t] : 0.f;
    float q2 = (MODE == 2 && t < NRED) ? n2p2[t] : 0.f;
#pragma unroll
    for (int m = 32; m >= 1; m >>= 1) {
        q1 += __shfl_xor(q1, m, 64);
        if (MODE == 2) q2 += __shfl_xor(q2, m, 64);
    }
    if (lane == 0) { redW[wid] = q1; redW[4 + wid] = q2; }
    __syncthreads();
    float n2a = (redW[0] + redW[1]) + (redW[2] + redW[3]);
    float sc1 = sqrtf(n2a) / (1.0f + n2a);

    // v_eff[n,b,:] (packed)
    f32x2 v2[8];
    {
        const f32x2* s1p = reinterpret_cast<const f32x2*>(s1)
                         + ((size_t)n * BATCH + t) * 8;
        f32x2 sv = {sc1, sc1};
#pragma unroll
        for (int j = 0; j < 8; ++j) v2[j] = s1p[j] * sv;
        if (MODE == 2) {
            float n2b = (redW[4] + redW[5]) + (redW[6] + redW[7]);
            float sc2 = sqrtf(n2b) / (1.0f + n2b);
            const f32x2* s2p = reinterpret_cast<const f32x2*>(s2)
                             + ((size_t)n * BATCH + t) * 8;
            f32x2 sw = {sc2, sc2};
#pragma unroll
            for (int j = 0; j < 8; ++j) v2[j] += s2p[j] * sw;
        }
    }

    f32x2 sp2[8];
#pragma unroll
    for (int j = 0; j < 8; ++j) sp2[j] = (f32x2){0.f, 0.f};

    for (int pr = 0; pr < CH / 2; ++pr) {
        int i = i0 + 2 * pr;        // pair {i, i+1}
        const float4* xp = reinterpret_cast<const float4*>(xT)
                         + ((size_t)i * BATCH + t) * 2;
        float4 xa0 = xp[0], xb0 = xp[1];
        float4 xa1 = xp[2 * BATCH], xb1 = xp[2 * BATCH + 1];
        float xr0[8] = {xa0.x, xa0.y, xa0.z, xa0.w, xb0.x, xb0.y, xb0.z, xb0.w};
        float xr1[8] = {xa1.x, xa1.y, xa1.z, xa1.w, xb1.x, xb1.y, xb1.z, xb1.w};
        const f32x2* wp2 = reinterpret_cast<const f32x2*>(
            w + (size_t)__builtin_amdgcn_readfirstlane((n * IC + i) * (LDIM * OC)));

        f32x2 pA[8], pB[8];
#pragma unroll
        for (int j = 0; j < 8; ++j) { pA[j] = (f32x2){0.f,0.f}; pB[j] = (f32x2){0.f,0.f}; }
#pragma unroll
        for (int l = 0; l < LDIM; ++l) {
            f32x2 x0 = {xr0[l], xr0[l]}, x1 = {xr1[l], xr1[l]};
#pragma unroll
            for (int j = 0; j < 8; ++j) {
                pA[j] += wp2[l * 8 + j] * x0;            // i
                pB[j] += wp2[64 + l * 8 + j] * x1;       // i+1 (adjacent w row)
            }
        }

        f32x2 dA = pA[0] * v2[0], dB = pB[0] * v2[0];
#pragma unroll
        for (int j = 1; j < 8; ++j) { dA += pA[j] * v2[j]; dB += pB[j] * v2[j]; }
        float betaA = dA.x + dA.y, betaB = dB.x + dB.y;   // beta_k = p . v_eff

        // in-block softmax over b: two independent chains, ILP-2, ONE barrier
        float eA = __expf(betaA), eB = __expf(betaB);
        float esA = eA, esB = eB;
#pragma unroll
        for (int m = 1; m < 64; m <<= 1) {
            esA += __shfl_xor(esA, m, 64);
            esB += __shfl_xor(esB, m, 64);
        }
        if (lane == 0) { redA[pr & 1][0][wid] = esA; redA[pr & 1][1][wid] = esB; }
        __syncthreads();
        float denA = (redA[pr&1][0][0] + redA[pr&1][0][1])
                   + (redA[pr&1][0][2] + redA[pr&1][0][3]);
        float denB = (redA[pr&1][1][0] + redA[pr&1][1][1])
                   + (redA[pr&1][1][2] + redA[pr&1][1][3]);
        float cA = eA / denA, cB = eB / denB;
        f32x2 cA2 = {cA, cA}, cB2 = {cB, cB};
#pragma unroll
        for (int j = 0; j < 8; ++j) sp2[j] += cA2 * pA[j] + cB2 * pB[j];
    }

    float4* dst = reinterpret_cast<float4*>(s_part)
                + (((size_t)ch * NC + n) * BATCH + t) * 4;
    dst[0] = make_float4(sp2[0].x, sp2[0].y, sp2[1].x, sp2[1].y);
    dst[1] = make_float4(sp2[2].x, sp2[2].y, sp2[3].x, sp2[3].y);
    dst[2] = make_float4(sp2[4].x, sp2[4].y, sp2[5].x, sp2[5].y);
    dst[3] = make_float4(sp2[6].x, sp2[6].y, sp2[7].x, sp2[7].y);
}

// ---------------------------------------------------------------------------
// K_OUT: n2 from partials; out = s * scale
// ---------------------------------------------------------------------------
__global__ __launch_bounds__(256) void k_out(const float* __restrict__ s,
                                             const float* __restrict__ n2_part,
                                             float* __restrict__ out)
{
    __shared__ float redW[4];
    int t = threadIdx.x, lane = t & 63, wid = t >> 6;
    float q = (t < NRED) ? n2_part[t] : 0.f;
#pragma unroll
    for (int m = 32; m >= 1; m >>= 1) q += __shfl_xor(q, m, 64);
    if (lane == 0) redW[wid] = q;
    __syncthreads();
    float n2 = (redW[0] + redW[1]) + (redW[2] + redW[3]);
    float sc = sqrtf(n2) / (1.0f + n2);
    int idx = blockIdx.x * 256 + t;
    out[idx] = s[idx] * sc;
}

// ---------------------------------------------------------------------------
extern "C" void kernel_launch(void* const* d_in, const int* in_sizes, int n_in,
                              void* d_out, int out_size, void* d_ws, size_t ws_size,
                              hipStream_t stream)
{
    const float* x = (const float*)d_in[0];   // [256,1152,8]
    const float* w = (const float*)d_in[1];   // [10,1152,8,16]
    float* out = (float*)d_out;               // 40960 floats
    float* ws  = (float*)d_ws;

    float* xT      = ws;                                  // 2,359,296
    float* s_part  = xT + (size_t)IC * BATCH * LDIM;      // 3,932,160
    float* s1      = s_part + (size_t)NCH * NTOT;         //    40,960
    float* s2      = s1 + NTOT;                           //    40,960
    float* s3      = s2 + NTOT;                           //    40,960
    float* n2p1    = s3 + NTOT;                           //       160
    float* n2p2    = n2p1 + NRED;                         //       160
    float* n2p3    = n2p2 + NRED;                         //       160
    // total ~26 MB of workspace

    dim3 blk(256);

    k0_xT<<<2304, blk, 0, stream>>>(x, xT);
    // iter 1: c uniform
    kA<<<NBLK, blk, 0, stream>>>(xT, w, s_part);
    kR<<<NRED, blk, 0, stream>>>(s_part, s1, n2p1);
    // iter 2: beta1 = p.v1
    kB<1><<<NBLK, blk, 0, stream>>>(xT, w, s1, n2p1, s1, n2p1, s_part);
    kR<<<NRED, blk, 0, stream>>>(s_part, s2, n2p2);
    // iter 3: beta2 = p.(v1+v2) (linearity, no beta carrier)
    kB<2><<<NBLK, blk, 0, stream>>>(xT, w, s1, n2p1, s2, n2p2, s_part);
    kR<<<NRED, blk, 0, stream>>>(s_part, s3, n2p3);
    // final squash -> out
    k_out<<<NRED, blk, 0, stream>>>(s3, n2p3, out);
}